// Round 2
// baseline (666.315 us; speedup 1.0000x reference)
//
#include <hip/hip_runtime.h>
#include <stdint.h>

// Problem (fp32 in / fp32 out): out = relu((x + (x@Wv^T+bv)@Wo^T + bo) @ Wn^T + bn)
//   softmax over a single score == 1 -> q,k path is dead code.
// Reformulated: out = relu(x@Wn^T + v@Wm^T + biasTot)
//   v  = x@Wv^T + bv          [8192 x 64]
//   Wm = Wn @ Wo              [4096 x 64]
//   biasTot = bn + Wn @ bo    [4096]
// Compute in bf16 MFMA (fp32 accumulate): convert x/Wn/Wv to bf16 first.

typedef unsigned short u16;
typedef float f32x4 __attribute__((ext_vector_type(4)));
typedef __bf16 bf16x8 __attribute__((ext_vector_type(8)));
typedef u16 u16x8 __attribute__((ext_vector_type(8)));

__device__ __forceinline__ float b2f(u16 u) {
  union { unsigned int i; float f; } x; x.i = ((unsigned int)u) << 16; return x.f;
}
__device__ __forceinline__ u16 f2b(float f) {  // round-to-nearest-even
  union { float f; unsigned int i; } x; x.f = f;
  unsigned int r = x.i + 0x7FFFu + ((x.i >> 16) & 1u);
  return (u16)(r >> 16);
}

// async global->LDS, 16B per lane; lds base wave-uniform (lane lands at base + lane*16B)
__device__ __forceinline__ void gl_lds16(const u16* g, u16* l) {
#if __has_builtin(__builtin_amdgcn_global_load_lds)
  __builtin_amdgcn_global_load_lds((__attribute__((address_space(1))) void*)g,
                                   (__attribute__((address_space(3))) void*)l, 16, 0, 0);
#else
  int lane = threadIdx.x & 63;
  *(u16x8*)(l + lane * 8) = *(const u16x8*)g;
#endif
}

__device__ __forceinline__ f32x4 mfma16(bf16x8 a, bf16x8 b, f32x4 c) {
  return __builtin_amdgcn_mfma_f32_16x16x32_bf16(a, b, c, 0, 0, 0);
}

// ---------------------------------------------------------------------------
// k_cvt: fp32 -> bf16 for x (33.5M), Wn (16.7M), Wv (262K). 8 floats/thread.
// ---------------------------------------------------------------------------
#define XCH 4194304L   // 33554432/8
#define WNCH 2097152L  // 16777216/8
#define WVCH 32768L    // 262144/8
__global__ __launch_bounds__(256) void k_cvt(
    const float* __restrict__ x, const float* __restrict__ Wn, const float* __restrict__ Wv,
    u16* __restrict__ xb, u16* __restrict__ Wnb, u16* __restrict__ Wvb) {
  long i = (long)blockIdx.x * 256 + threadIdx.x;
  const float* src; u16* dst; long off;
  if (i < XCH) { src = x; dst = xb; off = i * 8; }
  else if (i < XCH + WNCH) { src = Wn; dst = Wnb; off = (i - XCH) * 8; }
  else { src = Wv; dst = Wvb; off = (i - XCH - WNCH) * 8; }
  f32x4 a = *(const f32x4*)&src[off];
  f32x4 b = *(const f32x4*)&src[off + 4];
  u16x8 o;
#pragma unroll
  for (int e = 0; e < 4; ++e) { o[e] = f2b(a[e]); o[4 + e] = f2b(b[e]); }
  *(u16x8*)&dst[off] = o;
}

// ---------------------------------------------------------------------------
// kT: WoT[a][k] = bf16(Wo[k][a])  (Wo fp32 [4096 x 64]) -> K-contiguous B rows
// ---------------------------------------------------------------------------
__global__ __launch_bounds__(256) void kT(const float* __restrict__ Wo, u16* __restrict__ WoT) {
  __shared__ __align__(16) u16 t[64 * 72];  // 64x64 tile, padded stride 72
  const int b = blockIdx.x;                 // k-chunk of 64
  const int tid = threadIdx.x;
  {
    int k = tid >> 2, a0 = (tid & 3) * 16;
    const float* src = &Wo[(size_t)(b * 64 + k) * 64 + a0];
#pragma unroll
    for (int q = 0; q < 4; ++q) {
      f32x4 v = *(const f32x4*)&src[q * 4];
#pragma unroll
      for (int e = 0; e < 4; ++e) t[k * 72 + a0 + q * 4 + e] = f2b(v[e]);
    }
  }
  __syncthreads();
  {
    int a = tid >> 2, k0 = (tid & 3) * 16;
    u16x8 o0, o1;
#pragma unroll
    for (int j = 0; j < 8; ++j) o0[j] = t[(k0 + j) * 72 + a];
#pragma unroll
    for (int j = 0; j < 8; ++j) o1[j] = t[(k0 + 8 + j) * 72 + a];
    *(u16x8*)&WoT[(size_t)a * 4096 + b * 64 + k0] = o0;
    *(u16x8*)&WoT[(size_t)a * 4096 + b * 64 + k0 + 8] = o1;
  }
}

// ---------------------------------------------------------------------------
// gemm_n64: C[m0..m0+64][0..64] = A[m0..][0..4096] @ Brows^T (+bias fp32), bf16 out
//   A rows stride 4096 (bf16), B = 64 rows x 4096 (bf16, K-contiguous). BK=128.
//   XOR-swizzle 16B slots by (row&15) to kill bank conflicts on 256B LDS rows.
// ---------------------------------------------------------------------------
#define PBK 128
__device__ void gemm_n64(const u16* __restrict__ A, const u16* __restrict__ B,
                         u16* __restrict__ C, const float* __restrict__ bias,
                         long m0, u16* lA, u16* lB) {
  const int tid = threadIdx.x;
  const int w = tid >> 6, l = tid & 63;
  f32x4 acc[4];
#pragma unroll
  for (int nt = 0; nt < 4; ++nt) acc[nt] = (f32x4)(0.f);

  for (int k0 = 0; k0 < 4096; k0 += PBK) {
    __syncthreads();
#pragma unroll
    for (int i = 0; i < 4; ++i) {
      int row = w * 16 + i * 4 + (l >> 4);          // row within 64-row tile
      int p = (l & 15) ^ (i * 4 + (l >> 4));        // swizzled global 16B-slot
      gl_lds16(A + (m0 + row) * (long)4096 + k0 + p * 8, lA + (w * 16 + i * 4) * PBK);
      gl_lds16(B + (long)row * 4096 + k0 + p * 8, lB + (w * 16 + i * 4) * PBK);
    }
    __syncthreads();
#pragma unroll
    for (int kk = 0; kk < 4; ++kk) {
      int slotA = ((kk * 4 + (l >> 4)) ^ (l & 15)) * 8;
      bf16x8 af = *(const bf16x8*)&lA[(w * 16 + (l & 15)) * PBK + slotA];
#pragma unroll
      for (int nt = 0; nt < 4; ++nt) {
        bf16x8 bf = *(const bf16x8*)&lB[(nt * 16 + (l & 15)) * PBK + slotA];
        acc[nt] = mfma16(af, bf, acc[nt]);
      }
    }
  }
  // epilogue: C/D layout col=l&15, row=(l>>4)*4+r; scattered 2B stores (tiny output)
#pragma unroll
  for (int nt = 0; nt < 4; ++nt) {
    int col = nt * 16 + (l & 15);
    float bb = bias ? bias[col] : 0.f;
#pragma unroll
    for (int r = 0; r < 4; ++r) {
      long row = m0 + w * 16 + (l >> 4) * 4 + r;
      C[row * 64 + col] = f2b(acc[nt][r] + bb);
    }
  }
}

// ---------------------------------------------------------------------------
// k_prep: blocks [0,128): V = xb@Wvb^T+bv ; [128,192): Wm = Wnb@WoT^T ;
//         [192,1216): biasTot[n] = bn[n] + dot(bo, Wnb[n])  (one wave per n)
// ---------------------------------------------------------------------------
__global__ __launch_bounds__(256, 2) void k_prep(
    const u16* __restrict__ xb, const u16* __restrict__ Wvb, const float* __restrict__ bv,
    const u16* __restrict__ Wnb, const u16* __restrict__ WoT,
    const float* __restrict__ bo, const float* __restrict__ bn,
    u16* __restrict__ V, u16* __restrict__ Wm, float* __restrict__ biasTot) {
  __shared__ __align__(16) u16 lA[64 * PBK];
  __shared__ __align__(16) u16 lB[64 * PBK];
  const int bid = blockIdx.x;
  if (bid < 128) {
    gemm_n64(xb, Wvb, V, bv, (long)bid * 64, lA, lB);
  } else if (bid < 192) {
    gemm_n64(Wnb, WoT, Wm, nullptr, (long)(bid - 128) * 64, lA, lB);
  } else {
    const int w = threadIdx.x >> 6, l = threadIdx.x & 63;
    const int n = (bid - 192) * 4 + w;
    float s = 0.f;
#pragma unroll
    for (int j = 0; j < 8; ++j) {
      int off = (j * 64 + l) * 8;
      u16x8 a = *(const u16x8*)&Wnb[(size_t)n * 4096 + off];
      f32x4 c0 = *(const f32x4*)&bo[off];
      f32x4 c1 = *(const f32x4*)&bo[off + 4];
#pragma unroll
      for (int e = 0; e < 4; ++e) s += b2f(a[e]) * c0[e] + b2f(a[4 + e]) * c1[e];
    }
#pragma unroll
    for (int o = 32; o > 0; o >>= 1) s += __shfl_xor(s, o, 64);
    if (l == 0) biasTot[n] = s + bn[n];
  }
}

// ---------------------------------------------------------------------------
// k_main: out = relu(xb@Wnb^T + V@Wm^T + biasTot), m97 structure:
//   128x128 tile, BK=32, 4 waves 2x2 (64x64 each, 4x4 acc of 16x16x32 MFMA),
//   global_load_lds(16B) staging, augmented K tail (V/Wm, K=64),
//   fp32 output via per-wave LDS transpose -> coalesced dwordx4 stores.
// ---------------------------------------------------------------------------
__global__ __launch_bounds__(256, 2) void k_main(
    const u16* __restrict__ X, const u16* __restrict__ Wn,
    const u16* __restrict__ V, const u16* __restrict__ Wm,
    const float* __restrict__ biasTot, float* __restrict__ Out) {
  __shared__ __align__(16) u16 smem[2 * 128 * 32];  // 16 KB: staging A|B, reused by epilogue
  u16* lA = smem;
  u16* lB = smem + 128 * 32;
  const int tid = threadIdx.x;
  const int w = tid >> 6, l = tid & 63;
  const int wRow = (w & 1) * 64, wCol = (w >> 1) * 64;
  const long mBase = (long)(blockIdx.x >> 5) * 128;   // 64 m-blocks
  const int nBase = (int)(blockIdx.x & 31) * 128;     // 32 n-blocks

  f32x4 acc[4][4];
#pragma unroll
  for (int mt = 0; mt < 4; ++mt)
#pragma unroll
    for (int nt = 0; nt < 4; ++nt) acc[mt][nt] = (f32x4)(0.f);

  const int rl = l >> 2;          // row within 16-row staging instr
  const int kp = (l & 3) * 8;     // 16B slot within 64B row

  // K segment 1: A=xb (lda 4096), B=Wnb rows (ldb 4096)
  for (int k0 = 0; k0 < 4096; k0 += 32) {
    __syncthreads();
#pragma unroll
    for (int i = 0; i < 2; ++i) {
      int row = w * 32 + i * 16 + rl;
      gl_lds16(X + (mBase + row) * (long)4096 + k0 + kp, lA + (w * 32 + i * 16) * 32);
      gl_lds16(Wn + (long)(nBase + row) * 4096 + k0 + kp, lB + (w * 32 + i * 16) * 32);
    }
    __syncthreads();
    bf16x8 af[4], bfr[4];
#pragma unroll
    for (int mt = 0; mt < 4; ++mt)
      af[mt] = *(const bf16x8*)&lA[(wRow + mt * 16 + (l & 15)) * 32 + (l >> 4) * 8];
#pragma unroll
    for (int nt = 0; nt < 4; ++nt)
      bfr[nt] = *(const bf16x8*)&lB[(wCol + nt * 16 + (l & 15)) * 32 + (l >> 4) * 8];
#pragma unroll
    for (int mt = 0; mt < 4; ++mt)
#pragma unroll
      for (int nt = 0; nt < 4; ++nt) acc[mt][nt] = mfma16(af[mt], bfr[nt], acc[mt][nt]);
  }

  // K segment 2 (rank-64 correction): A=V (lda 64), B=Wm rows (ldb 64)
  for (int k0 = 0; k0 < 64; k0 += 32) {
    __syncthreads();
#pragma unroll
    for (int i = 0; i < 2; ++i) {
      int row = w * 32 + i * 16 + rl;
      gl_lds16(V + (mBase + row) * (long)64 + k0 + kp, lA + (w * 32 + i * 16) * 32);
      gl_lds16(Wm + (long)(nBase + row) * 64 + k0 + kp, lB + (w * 32 + i * 16) * 32);
    }
    __syncthreads();
    bf16x8 af[4], bfr[4];
#pragma unroll
    for (int mt = 0; mt < 4; ++mt)
      af[mt] = *(const bf16x8*)&lA[(wRow + mt * 16 + (l & 15)) * 32 + (l >> 4) * 8];
#pragma unroll
    for (int nt = 0; nt < 4; ++nt)
      bfr[nt] = *(const bf16x8*)&lB[(wCol + nt * 16 + (l & 15)) * 32 + (l >> 4) * 8];
#pragma unroll
    for (int mt = 0; mt < 4; ++mt)
#pragma unroll
      for (int nt = 0; nt < 4; ++nt) acc[mt][nt] = mfma16(af[mt], bfr[nt], acc[mt][nt]);
  }

  // epilogue: bias + relu, fp32; per-wave LDS transpose (4 KB/wave), dwordx4 stores
  __syncthreads();
  float* eb = ((float*)smem) + w * 1024;  // 16 rows x 64 cols fp32 per wave
#pragma unroll
  for (int mt = 0; mt < 4; ++mt) {
#pragma unroll
    for (int nt = 0; nt < 4; ++nt) {
      float bt = biasTot[nBase + wCol + nt * 16 + (l & 15)];
#pragma unroll
      for (int r = 0; r < 4; ++r) {
        float val = acc[mt][nt][r] + bt;
        eb[((l >> 4) * 4 + r) * 64 + nt * 16 + (l & 15)] = fmaxf(val, 0.f);
      }
    }
    int rr = l >> 2, c0 = (l & 3) * 16;
    long grow = mBase + wRow + mt * 16 + rr;
    int gcol = nBase + wCol + c0;
    f32x4 o0 = *(const f32x4*)&eb[rr * 64 + c0];
    f32x4 o1 = *(const f32x4*)&eb[rr * 64 + c0 + 4];
    f32x4 o2 = *(const f32x4*)&eb[rr * 64 + c0 + 8];
    f32x4 o3 = *(const f32x4*)&eb[rr * 64 + c0 + 12];
    *(f32x4*)&Out[grow * 4096 + gcol] = o0;
    *(f32x4*)&Out[grow * 4096 + gcol + 4] = o1;
    *(f32x4*)&Out[grow * 4096 + gcol + 8] = o2;
    *(f32x4*)&Out[grow * 4096 + gcol + 12] = o3;
  }
}

// ---------------------------------------------------------------------------
extern "C" void kernel_launch(void* const* d_in, const int* in_sizes, int n_in,
                              void* d_out, int out_size, void* d_ws, size_t ws_size,
                              hipStream_t stream) {
  const float* x  = (const float*)d_in[0];
  const float* Wv = (const float*)d_in[5];
  const float* bv = (const float*)d_in[6];
  const float* Wo = (const float*)d_in[7];
  const float* bo = (const float*)d_in[8];
  const float* Wn = (const float*)d_in[9];
  const float* bn = (const float*)d_in[10];
  float* out = (float*)d_out;

  char* ws = (char*)d_ws;
  u16* xb  = (u16*)ws;                            // 8192*4096*2 = 64 MB
  u16* Wnb = (u16*)(ws + (64L << 20));            // 4096*4096*2 = 32 MB
  u16* Wvb = (u16*)(ws + (96L << 20));            // 64*4096*2   = 512 KB
  u16* WoT = (u16*)(ws + (96L << 20) + (512 << 10));   // 512 KB
  u16* V   = (u16*)(ws + (97L << 20));            // 8192*64*2   = 1 MB
  u16* Wm  = (u16*)(ws + (98L << 20));            // 4096*64*2   = 512 KB
  float* biasTot = (float*)(ws + (98L << 20) + (512 << 10));  // 16 KB

  k_cvt<<<dim3(24704), dim3(256), 0, stream>>>(x, Wn, Wv, xb, Wnb, Wvb);
  kT<<<dim3(64), dim3(256), 0, stream>>>(Wo, WoT);
  k_prep<<<dim3(1216), dim3(256), 0, stream>>>(xb, Wvb, bv, Wnb, WoT, bo, bn, V, Wm, biasTot);
  k_main<<<dim3(2048), dim3(256), 0, stream>>>(xb, Wnb, V, Wm, biasTot, out);
}